// Round 1
// baseline (408.045 us; speedup 1.0000x reference)
//
#include <hip/hip_runtime.h>
#include <hip/hip_bf16.h>
#include <cstdint>

#define B_   8
#define C_   128
#define H_   64
#define W_   64
#define NPT  9
#define OC   256
#define K_   (C_*NPT)   // 1152
#define HW   (H_*W_)    // 4096
#define MTOT (B_*HW)    // 32768

typedef __attribute__((ext_vector_type(8))) short short8;
typedef __attribute__((ext_vector_type(4))) float f32x4;

// ---------------- Kernel A: offset conv (3x3, Cin=128, Cout=18, zero pad) ----------------
__global__ __launch_bounds__(256) void k_offset(const float* __restrict__ x,
                                                const float* __restrict__ pw,
                                                const float* __restrict__ pb,
                                                float* __restrict__ off) {
    int b = blockIdx.x >> 6;
    int i = blockIdx.x & 63;
    int tid = threadIdx.x;
    int j = tid & 63;
    int cq = tid >> 6;          // wave id: channel quarter
    float acc[18];
#pragma unroll
    for (int o = 0; o < 18; ++o) acc[o] = 0.f;
    const float* xb = x + (size_t)b * C_ * HW;
    for (int c = cq * 32; c < cq * 32 + 32; ++c) {
        const float* xc = xb + (size_t)c * HW;
#pragma unroll
        for (int kh = 0; kh < 3; ++kh) {
            int r = i + kh - 1;
            float x0 = 0.f, x1 = 0.f, x2 = 0.f;
            if (r >= 0 && r < H_) {
                const float* xr = xc + r * W_;
                x1 = xr[j];
                x0 = (j > 0)  ? xr[j - 1] : 0.f;
                x2 = (j < 63) ? xr[j + 1] : 0.f;
            }
            const float* wp = pw + c * 9 + kh * 3;  // w[oc][c][kh][kw] flat: oc*1152 + c*9 + kh*3 + kw
#pragma unroll
            for (int o = 0; o < 18; ++o) {
                acc[o] += wp[o * K_ + 0] * x0 + wp[o * K_ + 1] * x1 + wp[o * K_ + 2] * x2;
            }
        }
    }
    __shared__ float red[4][18 * 64];
#pragma unroll
    for (int o = 0; o < 18; ++o) red[cq][o * 64 + j] = acc[o];
    __syncthreads();
    for (int e = tid; e < 18 * 64; e += 256) {
        float v = red[0][e] + red[1][e] + red[2][e] + red[3][e] + pb[e >> 6];
        off[(((size_t)b * 18 + (e >> 6)) * H_ + i) * W_ + (e & 63)] = v;
    }
}

// ---------------- Kernel W: fold BN scale into bf16 weights [oc][k], bias[oc] ----------------
__global__ __launch_bounds__(256) void k_prepw(const float* __restrict__ cw,
                                               const float* __restrict__ gam,
                                               const float* __restrict__ bet,
                                               const float* __restrict__ mu,
                                               const float* __restrict__ var,
                                               __hip_bfloat16* __restrict__ wbf,
                                               float* __restrict__ bias) {
    int idx = blockIdx.x * 256 + threadIdx.x;   // 0 .. 294911
    int oc = idx / K_;
    float sc = gam[oc] * rsqrtf(var[oc] + 1e-5f);
    wbf[idx] = __float2bfloat16(cw[idx] * sc);
    if (blockIdx.x == 0 && threadIdx.x < OC) {
        int o = threadIdx.x;
        float s = gam[o] * rsqrtf(var[o] + 1e-5f);
        bias[o] = bet[o] - mu[o] * s;
    }
}

// ---------------- Kernel G: bilinear gather -> x_off [px][k] bf16 ----------------
#define GPX 16
__global__ __launch_bounds__(256) void k_gather(const float* __restrict__ x,
                                                const float* __restrict__ off,
                                                __hip_bfloat16* __restrict__ xoff) {
    int px0 = blockIdx.x * GPX;         // 16 consecutive px share (b, i)
    int b = px0 >> 12;
    int ij = px0 & 4095;
    int i = ij >> 6, j0 = ij & 63;
    __shared__ int   sIdx[4][GPX * NPT];
    __shared__ float sWt[4][GPX * NPT];
    int t = threadIdx.x;
    if (t < GPX * NPT) {                // 144 point-tasks
        int p = t / NPT, n = t - p * NPT;
        int j = j0 + p;
        const float* ob = off + (((size_t)b * 18) * H_ + i) * W_ + j;
        float ox = ob[(size_t)n * HW];
        float oy = ob[(size_t)(n + 9) * HW];
        float pxf = (float)(i + n / 3) + ox;    // p_n x = n/3, y = n%3
        float pyf = (float)(j + n % 3) + oy;
        float fx = floorf(pxf), fy = floorf(pyf);
        int ltx = max(0, min(63, (int)fx));
        int lty = max(0, min(63, (int)fy));
        int rbx = max(0, min(63, (int)fx + 1));
        int rby = max(0, min(63, (int)fy + 1));
        float pxc = fminf(fmaxf(pxf, 0.f), 63.f);
        float pyc = fminf(fmaxf(pyf, 0.f), 63.f);
        float ax = 1.f + ((float)ltx - pxc);
        float bx = 1.f - ((float)rbx - pxc);
        float ay = 1.f + ((float)lty - pyc);
        float by = 1.f - ((float)rby - pyc);
        sIdx[0][t] = ltx * 64 + lty;  sWt[0][t] = ax * ay;
        sIdx[1][t] = rbx * 64 + rby;  sWt[1][t] = bx * by;
        sIdx[2][t] = ltx * 64 + rby;  sWt[2][t] = ax * by;
        sIdx[3][t] = rbx * 64 + lty;  sWt[3][t] = bx * ay;
    }
    __syncthreads();
    const float* xb = x + (size_t)b * C_ * HW;
#pragma unroll 4
    for (int it = 0; it < GPX * K_ / 256; ++it) {   // 72 iterations
        int e = it * 256 + t;
        int p = e / K_;
        int k = e - p * K_;
        int c = k / NPT;
        int n = k - c * NPT;
        int r = p * NPT + n;
        const float* xc = xb + (size_t)c * HW;
        float v = sWt[0][r] * xc[sIdx[0][r]]
                + sWt[1][r] * xc[sIdx[1][r]]
                + sWt[2][r] * xc[sIdx[2][r]]
                + sWt[3][r] * xc[sIdx[3][r]];
        xoff[(size_t)px0 * K_ + e] = __float2bfloat16(v);
    }
}

// ---------------- Kernel M: bf16 MFMA GEMM  y[px][oc] = sum_k A[px][k]*Wt[oc][k] ----------------
#define BM 128
#define BN 128
#define BK 64
#define NTILES (K_ / BK)   // 18

__global__ __launch_bounds__(256) void k_gemm(const __hip_bfloat16* __restrict__ xoff,
                                              const __hip_bfloat16* __restrict__ wbf,
                                              const float* __restrict__ bias,
                                              float* __restrict__ out) {
    __shared__ __align__(16) char smem[2 * 2 * BM * BK * 2];  // 64 KiB: [buf][A/B][128 rows][128 B]
    int tid = threadIdx.x;
    int mt = blockIdx.x >> 1;
    int nt = blockIdx.x & 1;
    const char* Ab = (const char*)xoff + (size_t)mt * BM * (K_ * 2);
    const char* Bb = (const char*)wbf  + (size_t)nt * BN * (K_ * 2);

    auto stage = [&](int buf, int kt) {
        const int winByte = kt * (BK * 2);  // 128-byte k-window
#pragma unroll
        for (int q = 0; q < 4; ++q) {       // A tile: 1024 16B chunks
            int ch = q * 256 + tid;
            int row = ch >> 3, slot = ch & 7;
            int srcoff = row * (K_ * 2) + winByte + ((slot * 16) ^ ((row & 7) << 4));
            __builtin_amdgcn_global_load_lds(
                (const __attribute__((address_space(1))) uint32_t*)(Ab + srcoff),
                (__attribute__((address_space(3))) uint32_t*)(smem + buf * 32768 + ch * 16),
                16, 0, 0);
        }
#pragma unroll
        for (int q = 0; q < 4; ++q) {       // B tile
            int ch = q * 256 + tid;
            int row = ch >> 3, slot = ch & 7;
            int srcoff = row * (K_ * 2) + winByte + ((slot * 16) ^ ((row & 7) << 4));
            __builtin_amdgcn_global_load_lds(
                (const __attribute__((address_space(1))) uint32_t*)(Bb + srcoff),
                (__attribute__((address_space(3))) uint32_t*)(smem + buf * 32768 + 16384 + ch * 16),
                16, 0, 0);
        }
    };

    int wv = tid >> 6, lane = tid & 63;
    int wr = wv >> 1, wc = wv & 1;          // wave quadrant: 64 px × 64 oc
    int lrow = lane & 15, lg = lane >> 4;   // fragment row/col index, k-group

    f32x4 zero = {0.f, 0.f, 0.f, 0.f};
    f32x4 acc[4][4];
#pragma unroll
    for (int m = 0; m < 4; ++m)
#pragma unroll
        for (int n = 0; n < 4; ++n) acc[m][n] = zero;

    stage(0, 0);
    for (int kt = 0; kt < NTILES; ++kt) {
        if (kt + 1 < NTILES) stage((kt + 1) & 1, kt + 1);
        __syncthreads();   // drains vmcnt -> staged tile kt visible to all waves
        const char* sa = smem + (kt & 1) * 32768;
        const char* sb = sa + 16384;
#pragma unroll
        for (int kk = 0; kk < 2; ++kk) {
            short8 afr[4], bfr[4];
#pragma unroll
            for (int m = 0; m < 4; ++m) {
                int row = wr * 64 + m * 16 + lrow;
                int byt = kk * 64 + lg * 16;
                afr[m] = *(const short8*)(sa + row * 128 + (byt ^ ((row & 7) << 4)));
            }
#pragma unroll
            for (int n = 0; n < 4; ++n) {
                int row = wc * 64 + n * 16 + lrow;
                int byt = kk * 64 + lg * 16;
                bfr[n] = *(const short8*)(sb + row * 128 + (byt ^ ((row & 7) << 4)));
            }
#pragma unroll
            for (int m = 0; m < 4; ++m)
#pragma unroll
                for (int n = 0; n < 4; ++n)
                    acc[m][n] = __builtin_amdgcn_mfma_f32_16x16x32_bf16(afr[m], bfr[n], acc[m][n], 0, 0, 0);
        }
        __syncthreads();
    }

    // epilogue: bias + SiLU, scatter store (oc-major layout)
#pragma unroll
    for (int n = 0; n < 4; ++n) {
        int oc = nt * BN + wc * 64 + n * 16 + lrow;
        float bs = bias[oc];
#pragma unroll
        for (int m = 0; m < 4; ++m) {
            int pxb = mt * BM + wr * 64 + m * 16 + lg * 4;
#pragma unroll
            for (int r = 0; r < 4; ++r) {
                int px = pxb + r;
                float v = acc[m][n][r] + bs;
                float sv = v / (1.f + __expf(-v));
                out[((size_t)(px >> 12) * OC + oc) * HW + (px & 4095)] = sv;
            }
        }
    }
}

extern "C" void kernel_launch(void* const* d_in, const int* in_sizes, int n_in,
                              void* d_out, int out_size, void* d_ws, size_t ws_size,
                              hipStream_t stream) {
    const float* x   = (const float*)d_in[0];
    const float* pw  = (const float*)d_in[1];
    const float* pb  = (const float*)d_in[2];
    const float* cw  = (const float*)d_in[3];
    const float* gam = (const float*)d_in[4];
    const float* bet = (const float*)d_in[5];
    const float* mu  = (const float*)d_in[6];
    const float* var = (const float*)d_in[7];
    float* out = (float*)d_out;

    char* ws = (char*)d_ws;
    float* off           = (float*)ws;                           // 2,359,296 B
    __hip_bfloat16* wbf  = (__hip_bfloat16*)(ws + 2359296);      //   589,824 B
    float* bias          = (float*)(ws + 2949120);               //     1,024 B
    __hip_bfloat16* xoff = (__hip_bfloat16*)(ws + 2950144);      // 75,497,472 B

    hipLaunchKernelGGL(k_offset, dim3(512),  dim3(256), 0, stream, x, pw, pb, off);
    hipLaunchKernelGGL(k_prepw,  dim3(1152), dim3(256), 0, stream, cw, gam, bet, mu, var, wbf, bias);
    hipLaunchKernelGGL(k_gather, dim3(2048), dim3(256), 0, stream, x, off, xoff);
    hipLaunchKernelGGL(k_gemm,   dim3(512),  dim3(256), 0, stream, xoff, wbf, bias, out);
}

// Round 2
// 180.142 us; speedup vs baseline: 2.2651x; 2.2651x over previous
//
#include <hip/hip_runtime.h>
#include <hip/hip_bf16.h>
#include <cstdint>

#define B_   8
#define C_   128
#define H_   64
#define W_   64
#define NPT  9
#define OC   256
#define K_   (C_*NPT)   // 1152
#define HW   (H_*W_)    // 4096
#define MTOT (B_*HW)    // 32768

typedef __attribute__((ext_vector_type(8))) short short8;
typedef __attribute__((ext_vector_type(4))) float f32x4;
typedef __attribute__((ext_vector_type(4))) unsigned int u32x4;
typedef __attribute__((ext_vector_type(2))) unsigned int u32x2;

static __device__ __forceinline__ unsigned short f2bf(float f) {
    union { float f; unsigned u; } a; a.f = f;
    unsigned r = a.u + 0x7fffu + ((a.u >> 16) & 1u);   // RNE
    return (unsigned short)(r >> 16);
}
static __device__ __forceinline__ float bf2f(unsigned short u) {
    union { unsigned u; float f; } a; a.u = ((unsigned)u) << 16;
    return a.f;
}

// ---------------- Kernel A: offset conv (3x3, Cin=128, Cout=18, zero pad) ----------------
__global__ __launch_bounds__(256) void k_offset(const float* __restrict__ x,
                                                const float* __restrict__ pw,
                                                const float* __restrict__ pb,
                                                float* __restrict__ off) {
    int b = blockIdx.x >> 6;
    int i = blockIdx.x & 63;
    int tid = threadIdx.x;
    int j = tid & 63;
    int cq = tid >> 6;          // wave id: channel quarter
    float acc[18];
#pragma unroll
    for (int o = 0; o < 18; ++o) acc[o] = 0.f;
    const float* xb = x + (size_t)b * C_ * HW;
    for (int c = cq * 32; c < cq * 32 + 32; ++c) {
        const float* xc = xb + (size_t)c * HW;
#pragma unroll
        for (int kh = 0; kh < 3; ++kh) {
            int r = i + kh - 1;
            float x0 = 0.f, x1 = 0.f, x2 = 0.f;
            if (r >= 0 && r < H_) {
                const float* xr = xc + r * W_;
                x1 = xr[j];
                x0 = (j > 0)  ? xr[j - 1] : 0.f;
                x2 = (j < 63) ? xr[j + 1] : 0.f;
            }
            const float* wp = pw + c * 9 + kh * 3;  // w[oc][c][kh][kw] flat: oc*1152 + c*9 + kh*3 + kw
#pragma unroll
            for (int o = 0; o < 18; ++o) {
                acc[o] += wp[o * K_ + 0] * x0 + wp[o * K_ + 1] * x1 + wp[o * K_ + 2] * x2;
            }
        }
    }
    __shared__ float red[4][18 * 64];
#pragma unroll
    for (int o = 0; o < 18; ++o) red[cq][o * 64 + j] = acc[o];
    __syncthreads();
    for (int e = tid; e < 18 * 64; e += 256) {
        float v = red[0][e] + red[1][e] + red[2][e] + red[3][e] + pb[e >> 6];
        off[(((size_t)b * 18 + (e >> 6)) * H_ + i) * W_ + (e & 63)] = v;
    }
}

// ---------------- Kernel W: fold BN scale into bf16 weights, K reordered k = n*128 + c ----------------
__global__ __launch_bounds__(256) void k_prepw(const float* __restrict__ cw,
                                               const float* __restrict__ gam,
                                               const float* __restrict__ bet,
                                               const float* __restrict__ mu,
                                               const float* __restrict__ var,
                                               __hip_bfloat16* __restrict__ wbf,
                                               float* __restrict__ bias) {
    int idx = blockIdx.x * 256 + threadIdx.x;   // output index, 0 .. 294911
    int oc = idx / K_;
    int r = idx - oc * K_;
    int n = r >> 7;            // point index
    int c = r & 127;           // channel
    float sc = gam[oc] * rsqrtf(var[oc] + 1e-5f);
    wbf[idx] = __float2bfloat16(cw[oc * K_ + c * NPT + n] * sc);
    if (blockIdx.x == 0 && threadIdx.x < OC) {
        int o = threadIdx.x;
        float s = gam[o] * rsqrtf(var[o] + 1e-5f);
        bias[o] = bet[o] - mu[o] * s;
    }
}

// ---------------- Kernel G: LDS-staged bilinear gather -> x_off [px][n*128+c] bf16 ----------------
// Block = (batch, row-pair). Stages x rows i0-1..i0+4 (clamped) for all 128 ch as bf16.
__global__ __launch_bounds__(256) void k_gather(const float* __restrict__ x,
                                                const float* __restrict__ off,
                                                __hip_bfloat16* __restrict__ xoff) {
    // sx layout: byte addr = c*768 + (c>>6)*64 + s*128 + col*2   (c<128, s<6, col<64)
    __shared__ __align__(16) char sx[98368 + 64];
    __shared__ __align__(16) f32x4 swt[1152];     // [n*128+pxl] -> (w_lt, w_rb, w_lb, w_rt)
    __shared__ uint32_t scrd[1152];               // s0 | s1<<8 | c0<<16 | c1<<24
    int b = blockIdx.x >> 5;
    int i0 = (blockIdx.x & 31) * 2;
    int t = threadIdx.x;

    // ---- phase 1: stage x (coalesced float4 reads, bf16 LDS writes) ----
    const float* xb = x + (size_t)b * C_ * HW;
#pragma unroll 4
    for (int it = 0; it < 48; ++it) {
        int q = it * 256 + t;            // 0..12287 float4-chunks
        int c = q / 96;                  // 6 rows * 16 col4 per channel
        int rem = q - c * 96;
        int s = rem >> 4;
        int c4 = rem & 15;
        int gr = min(63, max(0, i0 - 1 + s));
        f32x4 v = *(const f32x4*)(xb + (size_t)c * HW + gr * 64 + c4 * 4);
        u32x2 pk;
        pk.x = (uint32_t)f2bf(v.x) | ((uint32_t)f2bf(v.y) << 16);
        pk.y = (uint32_t)f2bf(v.z) | ((uint32_t)f2bf(v.w) << 16);
        *(u32x2*)(sx + c * 768 + ((c >> 6) << 6) + s * 128 + c4 * 8) = pk;
    }

    // ---- phase 2: bilinear weights + coords per (px, n) ----
    for (int task = t; task < 1152; task += 256) {
        int n = task >> 7;
        int pxl = task & 127;
        int i = i0 + (pxl >> 6);
        int j = pxl & 63;
        const float* ob = off + (((size_t)b * 18 + n) * H_ + i) * W_ + j;
        float ox = ob[0];
        float oy = ob[9 * HW];
        float pxf = (float)(i + n / 3) + ox;
        float pyf = (float)(j + n % 3) + oy;
        float fx = floorf(pxf), fy = floorf(pyf);
        int r0 = max(0, min(63, (int)fx));
        int r1 = max(0, min(63, (int)fx + 1));
        int c0 = max(0, min(63, (int)fy));
        int c1 = max(0, min(63, (int)fy + 1));
        float pxc = fminf(fmaxf(pxf, 0.f), 63.f);
        float pyc = fminf(fmaxf(pyf, 0.f), 63.f);
        float ax = 1.f + ((float)r0 - pxc);
        float bx = 1.f - ((float)r1 - pxc);
        float ay = 1.f + ((float)c0 - pyc);
        float by = 1.f - ((float)c1 - pyc);
        f32x4 w; w.x = ax * ay; w.y = bx * by; w.z = ax * by; w.w = bx * ay;
        swt[task] = w;
        int s0 = max(0, min(5, r0 - (i0 - 1)));
        int s1 = max(0, min(5, r1 - (i0 - 1)));
        scrd[task] = (uint32_t)(s0 | (s1 << 8) | (c0 << 16) | (c1 << 24));
    }
    __syncthreads();

    // ---- phase 3: gather. thread -> (pxl, channel-half h); weights register-cached per n ----
    int wv = t >> 6;
    int h = (t >> 5) & 1;
    int pxl = wv * 32 + (t & 31);
    const char* sxh = sx + h * (64 * 768 + 64);       // channel-half base (incl. 64B skew)
    char* ob = (char*)xoff + ((size_t)blockIdx.x * 128 + pxl) * (K_ * 2) + h * 128;
    for (int n = 0; n < 9; ++n) {
        f32x4 w = swt[n * 128 + pxl];
        uint32_t crd = scrd[n * 128 + pxl];
        int s0 = crd & 255, s1 = (crd >> 8) & 255, c0 = (crd >> 16) & 255, c1 = crd >> 24;
        int o00 = s0 * 128 + c0 * 2;   // (r0,c0) -> w.x
        int o11 = s1 * 128 + c1 * 2;   // (r1,c1) -> w.y
        int o01 = s0 * 128 + c1 * 2;   // (r0,c1) -> w.z
        int o10 = s1 * 128 + c0 * 2;   // (r1,c0) -> w.w
        for (int cg = 0; cg < 8; ++cg) {
            u32x4 pk;
#pragma unroll
            for (int u2 = 0; u2 < 4; ++u2) {
                unsigned short r[2];
#pragma unroll
                for (int e = 0; e < 2; ++e) {
                    int cl = cg * 8 + u2 * 2 + e;         // channel within half
                    const char* base = sxh + cl * 768;
                    float v = w.x * bf2f(*(const unsigned short*)(base + o00))
                            + w.y * bf2f(*(const unsigned short*)(base + o11))
                            + w.z * bf2f(*(const unsigned short*)(base + o01))
                            + w.w * bf2f(*(const unsigned short*)(base + o10));
                    r[e] = f2bf(v);
                }
                pk[u2] = (uint32_t)r[0] | ((uint32_t)r[1] << 16);
            }
            *(u32x4*)(ob + n * 256 + cg * 16) = pk;
        }
    }
}

// ---------------- Kernel M: bf16 MFMA GEMM  y[px][oc] = sum_k A[px][k]*Wt[oc][k] ----------------
#define BM 128
#define BN 128
#define BK 64
#define NTILES (K_ / BK)   // 18

__global__ __launch_bounds__(256) void k_gemm(const __hip_bfloat16* __restrict__ xoff,
                                              const __hip_bfloat16* __restrict__ wbf,
                                              const float* __restrict__ bias,
                                              float* __restrict__ out) {
    __shared__ __align__(16) char smem[2 * 2 * BM * BK * 2];  // 64 KiB: [buf][A/B][128 rows][128 B]
    int tid = threadIdx.x;
    int mt = blockIdx.x >> 1;
    int nt = blockIdx.x & 1;
    const char* Ab = (const char*)xoff + (size_t)mt * BM * (K_ * 2);
    const char* Bb = (const char*)wbf  + (size_t)nt * BN * (K_ * 2);

    auto stage = [&](int buf, int kt) {
        const int winByte = kt * (BK * 2);  // 128-byte k-window
#pragma unroll
        for (int q = 0; q < 4; ++q) {       // A tile: 1024 16B chunks
            int ch = q * 256 + tid;
            int row = ch >> 3, slot = ch & 7;
            int srcoff = row * (K_ * 2) + winByte + ((slot * 16) ^ ((row & 7) << 4));
            __builtin_amdgcn_global_load_lds(
                (const __attribute__((address_space(1))) uint32_t*)(Ab + srcoff),
                (__attribute__((address_space(3))) uint32_t*)(smem + buf * 32768 + ch * 16),
                16, 0, 0);
        }
#pragma unroll
        for (int q = 0; q < 4; ++q) {       // B tile
            int ch = q * 256 + tid;
            int row = ch >> 3, slot = ch & 7;
            int srcoff = row * (K_ * 2) + winByte + ((slot * 16) ^ ((row & 7) << 4));
            __builtin_amdgcn_global_load_lds(
                (const __attribute__((address_space(1))) uint32_t*)(Bb + srcoff),
                (__attribute__((address_space(3))) uint32_t*)(smem + buf * 32768 + 16384 + ch * 16),
                16, 0, 0);
        }
    };

    int wv = tid >> 6, lane = tid & 63;
    int wr = wv >> 1, wc = wv & 1;          // wave quadrant: 64 px × 64 oc
    int lrow = lane & 15, lg = lane >> 4;   // fragment row index, k-group

    f32x4 zero = {0.f, 0.f, 0.f, 0.f};
    f32x4 acc[4][4];
#pragma unroll
    for (int m = 0; m < 4; ++m)
#pragma unroll
        for (int n = 0; n < 4; ++n) acc[m][n] = zero;

    stage(0, 0);
    for (int kt = 0; kt < NTILES; ++kt) {
        if (kt + 1 < NTILES) stage((kt + 1) & 1, kt + 1);
        __syncthreads();   // drains vmcnt -> staged tile kt visible to all waves
        const char* sa = smem + (kt & 1) * 32768;
        const char* sb = sa + 16384;
#pragma unroll
        for (int kk = 0; kk < 2; ++kk) {
            short8 afr[4], bfr[4];
#pragma unroll
            for (int m = 0; m < 4; ++m) {
                int row = wr * 64 + m * 16 + lrow;
                int byt = kk * 64 + lg * 16;
                afr[m] = *(const short8*)(sa + row * 128 + (byt ^ ((row & 7) << 4)));
            }
#pragma unroll
            for (int n = 0; n < 4; ++n) {
                int row = wc * 64 + n * 16 + lrow;
                int byt = kk * 64 + lg * 16;
                bfr[n] = *(const short8*)(sb + row * 128 + (byt ^ ((row & 7) << 4)));
            }
#pragma unroll
            for (int m = 0; m < 4; ++m)
#pragma unroll
                for (int n = 0; n < 4; ++n)
                    acc[m][n] = __builtin_amdgcn_mfma_f32_16x16x32_bf16(afr[m], bfr[n], acc[m][n], 0, 0, 0);
        }
        __syncthreads();
    }

    // epilogue: bias + SiLU, scatter store (oc-major layout)
#pragma unroll
    for (int n = 0; n < 4; ++n) {
        int oc = nt * BN + wc * 64 + n * 16 + lrow;
        float bs = bias[oc];
#pragma unroll
        for (int m = 0; m < 4; ++m) {
            int pxb = mt * BM + wr * 64 + m * 16 + lg * 4;
#pragma unroll
            for (int r = 0; r < 4; ++r) {
                int px = pxb + r;
                float v = acc[m][n][r] + bs;
                float sv = v / (1.f + __expf(-v));
                out[((size_t)(px >> 12) * OC + oc) * HW + (px & 4095)] = sv;
            }
        }
    }
}

extern "C" void kernel_launch(void* const* d_in, const int* in_sizes, int n_in,
                              void* d_out, int out_size, void* d_ws, size_t ws_size,
                              hipStream_t stream) {
    const float* x   = (const float*)d_in[0];
    const float* pw  = (const float*)d_in[1];
    const float* pb  = (const float*)d_in[2];
    const float* cw  = (const float*)d_in[3];
    const float* gam = (const float*)d_in[4];
    const float* bet = (const float*)d_in[5];
    const float* mu  = (const float*)d_in[6];
    const float* var = (const float*)d_in[7];
    float* out = (float*)d_out;

    char* ws = (char*)d_ws;
    float* off           = (float*)ws;                           // 2,359,296 B
    __hip_bfloat16* wbf  = (__hip_bfloat16*)(ws + 2359296);      //   589,824 B
    float* bias          = (float*)(ws + 2949120);               //     1,024 B
    __hip_bfloat16* xoff = (__hip_bfloat16*)(ws + 2950144);      // 75,497,472 B

    hipLaunchKernelGGL(k_offset, dim3(512),  dim3(256), 0, stream, x, pw, pb, off);
    hipLaunchKernelGGL(k_prepw,  dim3(1152), dim3(256), 0, stream, cw, gam, bet, mu, var, wbf, bias);
    hipLaunchKernelGGL(k_gather, dim3(256),  dim3(256), 0, stream, x, off, xoff);
    hipLaunchKernelGGL(k_gemm,   dim3(512),  dim3(256), 0, stream, xoff, wbf, bias, out);
}

// Round 4
// 108.611 us; speedup vs baseline: 3.7569x; 1.6586x over previous
//
#include <hip/hip_runtime.h>
#include <hip/hip_bf16.h>
#include <cstdint>

#define B_   8
#define C_   128
#define H_   64
#define W_   64
#define NPT  9
#define OC   256
#define K_   (C_*NPT)   // 1152
#define HW   (H_*W_)    // 4096
#define MTOT (B_*HW)    // 32768

typedef __attribute__((ext_vector_type(8))) short short8;
typedef __attribute__((ext_vector_type(4))) float f32x4;
typedef __attribute__((ext_vector_type(4))) unsigned int u32x4;
typedef __attribute__((ext_vector_type(2))) unsigned int u32x2;

static __device__ __forceinline__ unsigned short f2bf(float f) {
    union { float f; unsigned u; } a; a.f = f;
    unsigned r = a.u + 0x7fffu + ((a.u >> 16) & 1u);   // RNE
    return (unsigned short)(r >> 16);
}
static __device__ __forceinline__ float bf2f(unsigned short u) {
    union { unsigned u; float f; } a; a.u = ((unsigned)u) << 16;
    return a.f;
}

// ---------------- Kernel A: fp32 offset conv, LDS-staged weights ----------------
// block = (b, row-pair i0), 512 threads = (j 0..63, cg 0..7); thread: 2 px, 16 ch, 18 outs
__global__ __launch_bounds__(512) void k_offset2(const float* __restrict__ x,
                                                 const float* __restrict__ pw,
                                                 const float* __restrict__ pb,
                                                 float* __restrict__ off) {
    __shared__ __align__(16) float wlds[128 * 180];   // [c][tap][20 pad] = 92160 B
    __shared__ float red[8 * 64 * 19];                // [cg][j][19 pad]  = 38912 B
    int b = blockIdx.x >> 5;
    int i0 = (blockIdx.x & 31) * 2;
    int t = threadIdx.x;

    for (int idx = t; idx < 128 * 9 * 18; idx += 512) {
        int c = idx / 162;
        int r = idx - c * 162;
        int tap = r / 18;
        int o = r - tap * 18;
        wlds[c * 180 + tap * 20 + o] = pw[o * K_ + c * 9 + tap];
    }
    __syncthreads();

    int j = t & 63;
    int cg = t >> 6;
    const float* xb = x + (size_t)b * C_ * HW;
    float acc[2][18];
#pragma unroll
    for (int p = 0; p < 2; ++p)
#pragma unroll
        for (int o = 0; o < 18; ++o) acc[p][o] = 0.f;

    for (int cc = 0; cc < 16; ++cc) {
        int c = cg * 16 + cc;
        const float* xc = xb + (size_t)c * HW;
        float xv[4][3];
#pragma unroll
        for (int q = 0; q < 4; ++q) {
            int row = i0 - 1 + q;
            if (row >= 0 && row < H_) {
                const float* xr = xc + row * W_;
                xv[q][1] = xr[j];
                xv[q][0] = (j > 0)  ? xr[j - 1] : 0.f;
                xv[q][2] = (j < 63) ? xr[j + 1] : 0.f;
            } else {
                xv[q][0] = xv[q][1] = xv[q][2] = 0.f;
            }
        }
        const float* wc = wlds + c * 180;
#pragma unroll
        for (int tap = 0; tap < 9; ++tap) {
            const int kh = tap / 3, kw = tap % 3;
            float w18[20];
            *(f32x4*)(w18 + 0)  = *(const f32x4*)(wc + tap * 20 + 0);
            *(f32x4*)(w18 + 4)  = *(const f32x4*)(wc + tap * 20 + 4);
            *(f32x4*)(w18 + 8)  = *(const f32x4*)(wc + tap * 20 + 8);
            *(f32x4*)(w18 + 12) = *(const f32x4*)(wc + tap * 20 + 12);
            *(f32x4*)(w18 + 16) = *(const f32x4*)(wc + tap * 20 + 16);
#pragma unroll
            for (int p = 0; p < 2; ++p) {
                float xval = xv[p + kh][kw];
#pragma unroll
                for (int o = 0; o < 18; ++o) acc[p][o] += w18[o] * xval;
            }
        }
    }

    // 8-way reduction over cg, per px
#pragma unroll
    for (int p = 0; p < 2; ++p) {
        __syncthreads();
#pragma unroll
        for (int o = 0; o < 18; ++o) red[(cg * 64 + j) * 19 + o] = acc[p][o];
        __syncthreads();
        for (int e = t; e < 64 * 18; e += 512) {
            int jj = e / 18, o = e - jj * 18;
            float s = 0.f;
#pragma unroll
            for (int g = 0; g < 8; ++g) s += red[(g * 64 + jj) * 19 + o];
            off[(((size_t)b * 18 + o) * H_ + (i0 + p)) * W_ + jj] = s + pb[o];
        }
    }
}

// ---------------- Kernel W: fold BN scale into bf16 weights, K reordered k = n*128 + c ----------------
__global__ __launch_bounds__(256) void k_prepw(const float* __restrict__ cw,
                                               const float* __restrict__ gam,
                                               const float* __restrict__ bet,
                                               const float* __restrict__ mu,
                                               const float* __restrict__ var,
                                               __hip_bfloat16* __restrict__ wbf,
                                               float* __restrict__ bias) {
    int idx = blockIdx.x * 256 + threadIdx.x;   // output index, 0 .. 294911
    int oc = idx / K_;
    int r = idx - oc * K_;
    int n = r >> 7;            // point index
    int c = r & 127;           // channel
    float sc = gam[oc] * rsqrtf(var[oc] + 1e-5f);
    wbf[idx] = __float2bfloat16(cw[oc * K_ + c * NPT + n] * sc);
    if (blockIdx.x == 0 && threadIdx.x < OC) {
        int o = threadIdx.x;
        float s = gam[o] * rsqrtf(var[o] + 1e-5f);
        bias[o] = bet[o] - mu[o] * s;
    }
}

// ---------------- Kernel G: LDS-staged bilinear gather -> x_off [px][n*128+c] bf16 ----------------
__global__ __launch_bounds__(256) void k_gather(const float* __restrict__ x,
                                                const float* __restrict__ off,
                                                __hip_bfloat16* __restrict__ xoff) {
    // sx layout: byte addr = c*768 + (c>>6)*64 + s*128 + col*2   (c<128, s<6, col<64)
    __shared__ __align__(16) char sx[98368 + 64];
    __shared__ __align__(16) f32x4 swt[1152];     // [n*128+pxl] -> (w_lt, w_rb, w_lb, w_rt)
    __shared__ uint32_t scrd[1152];               // s0 | s1<<8 | c0<<16 | c1<<24
    int b = blockIdx.x >> 5;
    int i0 = (blockIdx.x & 31) * 2;
    int t = threadIdx.x;

    const float* xb = x + (size_t)b * C_ * HW;
#pragma unroll 4
    for (int it = 0; it < 48; ++it) {
        int q = it * 256 + t;            // 0..12287 float4-chunks
        int c = q / 96;                  // 6 rows * 16 col4 per channel
        int rem = q - c * 96;
        int s = rem >> 4;
        int c4 = rem & 15;
        int gr = min(63, max(0, i0 - 1 + s));
        f32x4 v = *(const f32x4*)(xb + (size_t)c * HW + gr * 64 + c4 * 4);
        u32x2 pk;
        pk.x = (uint32_t)f2bf(v.x) | ((uint32_t)f2bf(v.y) << 16);
        pk.y = (uint32_t)f2bf(v.z) | ((uint32_t)f2bf(v.w) << 16);
        *(u32x2*)(sx + c * 768 + ((c >> 6) << 6) + s * 128 + c4 * 8) = pk;
    }

    for (int task = t; task < 1152; task += 256) {
        int n = task >> 7;
        int pxl = task & 127;
        int i = i0 + (pxl >> 6);
        int j = pxl & 63;
        const float* ob = off + (((size_t)b * 18 + n) * H_ + i) * W_ + j;
        float ox = ob[0];
        float oy = ob[9 * HW];
        float pxf = (float)(i + n / 3) + ox;
        float pyf = (float)(j + n % 3) + oy;
        float fx = floorf(pxf), fy = floorf(pyf);
        int r0 = max(0, min(63, (int)fx));
        int r1 = max(0, min(63, (int)fx + 1));
        int c0 = max(0, min(63, (int)fy));
        int c1 = max(0, min(63, (int)fy + 1));
        float pxc = fminf(fmaxf(pxf, 0.f), 63.f);
        float pyc = fminf(fmaxf(pyf, 0.f), 63.f);
        float ax = 1.f + ((float)r0 - pxc);
        float bx = 1.f - ((float)r1 - pxc);
        float ay = 1.f + ((float)c0 - pyc);
        float by = 1.f - ((float)c1 - pyc);
        f32x4 w; w.x = ax * ay; w.y = bx * by; w.z = ax * by; w.w = bx * ay;
        swt[task] = w;
        int s0 = max(0, min(5, r0 - (i0 - 1)));
        int s1 = max(0, min(5, r1 - (i0 - 1)));
        scrd[task] = (uint32_t)(s0 | (s1 << 8) | (c0 << 16) | (c1 << 24));
    }
    __syncthreads();

    int wv = t >> 6;
    int h = (t >> 5) & 1;
    int pxl = wv * 32 + (t & 31);
    const char* sxh = sx + h * (64 * 768 + 64);       // channel-half base (incl. 64B skew)
    char* ob = (char*)xoff + ((size_t)blockIdx.x * 128 + pxl) * (K_ * 2) + h * 128;
    for (int n = 0; n < 9; ++n) {
        f32x4 w = swt[n * 128 + pxl];
        uint32_t crd = scrd[n * 128 + pxl];
        int s0 = crd & 255, s1 = (crd >> 8) & 255, c0 = (crd >> 16) & 255, c1 = crd >> 24;
        int o00 = s0 * 128 + c0 * 2;
        int o11 = s1 * 128 + c1 * 2;
        int o01 = s0 * 128 + c1 * 2;
        int o10 = s1 * 128 + c0 * 2;
        for (int cg = 0; cg < 8; ++cg) {
            u32x4 pk;
#pragma unroll
            for (int u2 = 0; u2 < 4; ++u2) {
                unsigned short r[2];
#pragma unroll
                for (int e = 0; e < 2; ++e) {
                    int cl = cg * 8 + u2 * 2 + e;
                    const char* base = sxh + cl * 768;
                    float v = w.x * bf2f(*(const unsigned short*)(base + o00))
                            + w.y * bf2f(*(const unsigned short*)(base + o11))
                            + w.z * bf2f(*(const unsigned short*)(base + o01))
                            + w.w * bf2f(*(const unsigned short*)(base + o10));
                    r[e] = f2bf(v);
                }
                pk[u2] = (uint32_t)r[0] | ((uint32_t)r[1] << 16);
            }
            *(u32x4*)(ob + n * 256 + cg * 16) = pk;
        }
    }
}

// ---------------- Kernel M: bf16 MFMA GEMM  y[px][oc] = sum_k A[px][k]*Wt[oc][k] ----------------
#define BM 128
#define BN 128
#define BK 64
#define NTILES (K_ / BK)   // 18

__global__ __launch_bounds__(256) void k_gemm(const __hip_bfloat16* __restrict__ xoff,
                                              const __hip_bfloat16* __restrict__ wbf,
                                              const float* __restrict__ bias,
                                              float* __restrict__ out) {
    __shared__ __align__(16) char smem[2 * 2 * BM * BK * 2];  // 64 KiB
    int tid = threadIdx.x;
    int mt = blockIdx.x >> 1;
    int nt = blockIdx.x & 1;
    const char* Ab = (const char*)xoff + (size_t)mt * BM * (K_ * 2);
    const char* Bb = (const char*)wbf  + (size_t)nt * BN * (K_ * 2);

    auto stage = [&](int buf, int kt) {
        const int winByte = kt * (BK * 2);
#pragma unroll
        for (int q = 0; q < 4; ++q) {
            int ch = q * 256 + tid;
            int row = ch >> 3, slot = ch & 7;
            int srcoff = row * (K_ * 2) + winByte + ((slot * 16) ^ ((row & 7) << 4));
            __builtin_amdgcn_global_load_lds(
                (const __attribute__((address_space(1))) uint32_t*)(Ab + srcoff),
                (__attribute__((address_space(3))) uint32_t*)(smem + buf * 32768 + ch * 16),
                16, 0, 0);
        }
#pragma unroll
        for (int q = 0; q < 4; ++q) {
            int ch = q * 256 + tid;
            int row = ch >> 3, slot = ch & 7;
            int srcoff = row * (K_ * 2) + winByte + ((slot * 16) ^ ((row & 7) << 4));
            __builtin_amdgcn_global_load_lds(
                (const __attribute__((address_space(1))) uint32_t*)(Bb + srcoff),
                (__attribute__((address_space(3))) uint32_t*)(smem + buf * 32768 + 16384 + ch * 16),
                16, 0, 0);
        }
    };

    int wv = tid >> 6, lane = tid & 63;
    int wr = wv >> 1, wc = wv & 1;
    int lrow = lane & 15, lg = lane >> 4;

    f32x4 zero = {0.f, 0.f, 0.f, 0.f};
    f32x4 acc[4][4];
#pragma unroll
    for (int m = 0; m < 4; ++m)
#pragma unroll
        for (int n = 0; n < 4; ++n) acc[m][n] = zero;

    stage(0, 0);
    for (int kt = 0; kt < NTILES; ++kt) {
        if (kt + 1 < NTILES) stage((kt + 1) & 1, kt + 1);
        __syncthreads();
        const char* sa = smem + (kt & 1) * 32768;
        const char* sb = sa + 16384;
#pragma unroll
        for (int kk = 0; kk < 2; ++kk) {
            short8 afr[4], bfr[4];
#pragma unroll
            for (int m = 0; m < 4; ++m) {
                int row = wr * 64 + m * 16 + lrow;
                int byt = kk * 64 + lg * 16;
                afr[m] = *(const short8*)(sa + row * 128 + (byt ^ ((row & 7) << 4)));
            }
#pragma unroll
            for (int n = 0; n < 4; ++n) {
                int row = wc * 64 + n * 16 + lrow;
                int byt = kk * 64 + lg * 16;
                bfr[n] = *(const short8*)(sb + row * 128 + (byt ^ ((row & 7) << 4)));
            }
#pragma unroll
            for (int m = 0; m < 4; ++m)
#pragma unroll
                for (int n = 0; n < 4; ++n)
                    acc[m][n] = __builtin_amdgcn_mfma_f32_16x16x32_bf16(afr[m], bfr[n], acc[m][n], 0, 0, 0);
        }
        __syncthreads();
    }

#pragma unroll
    for (int n = 0; n < 4; ++n) {
        int oc = nt * BN + wc * 64 + n * 16 + lrow;
        float bs = bias[oc];
#pragma unroll
        for (int m = 0; m < 4; ++m) {
            int pxb = mt * BM + wr * 64 + m * 16 + lg * 4;
#pragma unroll
            for (int r = 0; r < 4; ++r) {
                int px = pxb + r;
                float v = acc[m][n][r] + bs;
                float sv = v / (1.f + __expf(-v));
                out[((size_t)(px >> 12) * OC + oc) * HW + (px & 4095)] = sv;
            }
        }
    }
}

extern "C" void kernel_launch(void* const* d_in, const int* in_sizes, int n_in,
                              void* d_out, int out_size, void* d_ws, size_t ws_size,
                              hipStream_t stream) {
    const float* x   = (const float*)d_in[0];
    const float* pw  = (const float*)d_in[1];
    const float* pb  = (const float*)d_in[2];
    const float* cw  = (const float*)d_in[3];
    const float* gam = (const float*)d_in[4];
    const float* bet = (const float*)d_in[5];
    const float* mu  = (const float*)d_in[6];
    const float* var = (const float*)d_in[7];
    float* out = (float*)d_out;

    char* ws = (char*)d_ws;
    float* off           = (float*)ws;                           // 2,359,296 B
    __hip_bfloat16* wbf  = (__hip_bfloat16*)(ws + 2359296);      //   589,824 B
    float* bias          = (float*)(ws + 2949120);               //     1,024 B
    __hip_bfloat16* xoff = (__hip_bfloat16*)(ws + 2950144);      // 75,497,472 B

    hipLaunchKernelGGL(k_offset2, dim3(256),  dim3(512), 0, stream, x, pw, pb, off);
    hipLaunchKernelGGL(k_prepw,   dim3(1152), dim3(256), 0, stream, cw, gam, bet, mu, var, wbf, bias);
    hipLaunchKernelGGL(k_gather,  dim3(256),  dim3(256), 0, stream, x, off, xoff);
    hipLaunchKernelGGL(k_gemm,    dim3(512),  dim3(256), 0, stream, xoff, wbf, bias, out);
}